// Round 1
// baseline (156.592 us; speedup 1.0000x reference)
//
#include <hip/hip_runtime.h>
#include <math.h>

constexpr int B_ = 8192;
constexpr int N_ = 1024;
constexpr int NTHREADS = 256;
constexpr int WPB = NTHREADS / 64;        // 4 waves/block, one batch per wave
constexpr int NBLOCKS = B_ / WPB;         // 2048 blocks
constexpr float SCALE = 1.0f / ((float)B_ * (float)N_);
constexpr int ROWF = 3 * N_;              // floats per batch row (3072 = 12 KB)

// Native vector type (HIP_vector_type is rejected by some builtins).
typedef float vfloat4 __attribute__((ext_vector_type(4)));

// Address-space-qualified element types for global_load_lds.
typedef float GF __attribute__((address_space(1)));   // global
typedef float LF __attribute__((address_space(3)));   // LDS

// R = Rx(a) @ Ry(b) @ Rz(c), row-major 3x3 (matches reference euler_to_matrix_xyz)
__device__ __forceinline__ void euler_to_mat(float a, float b, float c, float R[9]) {
    float ca = cosf(a), sa = sinf(a);
    float cb = cosf(b), sb = sinf(b);
    float cc = cosf(c), sc = sinf(c);
    R[0] = cb * cc;                R[1] = -cb * sc;               R[2] = sb;
    R[3] = ca * sc + sa * sb * cc; R[4] = ca * cc - sa * sb * sc; R[5] = -sa * cb;
    R[6] = sa * sc - ca * sb * cc; R[7] = sa * cc + ca * sb * sc; R[8] = ca * cb;
}

__device__ __forceinline__ void compute_M(const float* __restrict__ pred,
                                          const float* __restrict__ mode,
                                          const float* __restrict__ gt,
                                          int b, float M[9]) {
    float m1 = pred[b * 4 + 0], m2 = pred[b * 4 + 1];
    float m3 = pred[b * 4 + 2], m4 = pred[b * 4 + 3];
    float sgn = (mode[b] > 0.5f) ? 1.0f : -1.0f;
    float e2 = sgn * asinf(sqrtf(m3 * m3 / (m1 * m1 + m2 * m2 + m3 * m3)));
    float e3 = atan2f(m4, m3 / (sinf(e2) + 1e-9f));
    float tmp = cosf(e2) * cosf(e3);
    float e1 = atan2f(m2 / tmp, m1 / tmp);
    e3 = (e3 > 0.0f) ? e3 : (e3 + 6.2831854820251465f); // float32(2*pi)
    float P[9], G[9];
    euler_to_mat(e1, e2, e3, P);
    euler_to_mat(gt[b * 3 + 0], gt[b * 3 + 1], gt[b * 3 + 2], G);
    #pragma unroll
    for (int i = 0; i < 9; ++i) M[i] = P[i] - G[i];
}

__device__ __forceinline__ float dist3(float px, float py, float pz, const float* M) {
    float dx = px * M[0] + py * M[3] + pz * M[6];
    float dy = px * M[1] + py * M[4] + pz * M[7];
    float dz = px * M[2] + py * M[5] + pz * M[8];
    return sqrtf(dx * dx + dy * dy + dz * dz);
}

// ---------- Main: one batch per wave; global->LDS staging; one dispatch ----------
// v2: replaced 12 stride-48B nontemporal dwordx4 loads (33% line utilization per
// instruction, nt hint defeating the L2 reuse the pattern depended on) with the
// canonical global_load_lds staging: 12 x 1KB lane-contiguous dwordx4 per wave,
// 100% line utilization per instruction, no VGPR round-trip. LDS reads reproduce
// the v1 per-lane point assignment and summation order exactly (bitwise-equal
// output). ~8-way LDS bank aliasing on the 48B-stride ds_read_b128 is hidden
// under HBM time (DS pipe ~5us/CU vs HBM ~15us/CU).
__global__ __launch_bounds__(NTHREADS)
void fused_main(const float* __restrict__ pred, const float* __restrict__ mode,
                const float* __restrict__ gt, const float* __restrict__ point,
                float* __restrict__ partial)          // (B_,) one entry per wave/batch
{
    __shared__ __align__(16) float smem[WPB * ROWF];  // 48 KB -> 3 blocks/CU
    const int wave = threadIdx.x >> 6;
    const int lane = threadIdx.x & 63;
    const int b    = blockIdx.x * WPB + wave;

    // 1) Stage this batch's 12 KB row: 12 instructions, each writes the wave's
    //    64 x 16 B = 1 KB contiguous (LDS dest = wave-uniform base + lane*16;
    //    global src = same linear order -> layouts match).
    {
        const float* src = point + (size_t)b * ROWF;
        float* dst = smem + wave * ROWF;
        #pragma unroll
        for (int i = 0; i < 12; ++i) {
            __builtin_amdgcn_global_load_lds(
                (const GF*)(src + i * 256 + lane * 4),
                (LF*)(dst + i * 256),
                16, 0, 0);
        }
    }

    // 2) M computed redundantly on all 64 lanes (wave-uniform -> zero divergence),
    //    overlapped with the 12 in-flight staging loads.
    float M[9];
    compute_M(pred, mode, gt, b, M);

    // 3) Barrier drains vmcnt(0) -> LDS contents valid (m97 pattern).
    __syncthreads();

    // 4) 16 points per lane, same order as v1: lane L handles points
    //    256*j + 4L .. +3 for j = 0..3. Aligned 16B LDS vector reads.
    const float* lrow = smem + wave * ROWF;
    float local = 0.0f;
    #pragma unroll
    for (int j = 0; j < 4; ++j) {
        const vfloat4 p0 = *(const vfloat4*)(lrow + j * 768 + lane * 12 + 0);
        const vfloat4 p1 = *(const vfloat4*)(lrow + j * 768 + lane * 12 + 4);
        const vfloat4 p2 = *(const vfloat4*)(lrow + j * 768 + lane * 12 + 8);
        local += dist3(p0.x, p0.y, p0.z, M)
               + dist3(p0.w, p1.x, p1.y, M)
               + dist3(p1.z, p1.w, p2.x, M)
               + dist3(p2.y, p2.z, p2.w, M);
    }

    // 5) Wave-local shuffle reduce; lane 0 stores this batch's sum.
    #pragma unroll
    for (int off = 32; off > 0; off >>= 1)
        local += __shfl_down(local, off, 64);
    if (lane == 0) partial[b] = local;
}

// ---------- Final: reduce 8192 partials -> scalar ----------
__global__ __launch_bounds__(1024)
void reduce_kernel(const float* __restrict__ partial, float* __restrict__ out) {
    __shared__ float swave[1024 / 64];
    const int t = threadIdx.x;
    float local = 0.0f;
    #pragma unroll
    for (int i = 0; i < B_ / 1024; ++i) local += partial[t + 1024 * i];
    #pragma unroll
    for (int off = 32; off > 0; off >>= 1)
        local += __shfl_down(local, off, 64);
    if ((t & 63) == 0) swave[t >> 6] = local;
    __syncthreads();
    if (t == 0) {
        float s = 0.0f;
        #pragma unroll
        for (int i = 0; i < 1024 / 64; ++i) s += swave[i];
        out[0] = s * SCALE;
    }
}

// ---------- Fallback (ws too small): v1 main, atomic into out ----------
__global__ __launch_bounds__(NTHREADS)
void fused_atomic(const float* __restrict__ pred, const float* __restrict__ mode,
                  const float* __restrict__ gt, const float* __restrict__ point,
                  float* __restrict__ out) {
    const int wave = threadIdx.x >> 6;
    const int lane = threadIdx.x & 63;
    const int b    = blockIdx.x * WPB + wave;
    const vfloat4* gp4 = (const vfloat4*)(point + (size_t)b * ROWF);
    vfloat4 P[4][3];
    #pragma unroll
    for (int j = 0; j < 4; ++j)
        #pragma unroll
        for (int k = 0; k < 3; ++k)
            P[j][k] = __builtin_nontemporal_load(&gp4[192 * j + 3 * lane + k]);
    float M[9];
    compute_M(pred, mode, gt, b, M);
    float local = 0.0f;
    #pragma unroll
    for (int j = 0; j < 4; ++j) {
        const vfloat4 p0 = P[j][0], p1 = P[j][1], p2 = P[j][2];
        local += dist3(p0.x, p0.y, p0.z, M)
               + dist3(p0.w, p1.x, p1.y, M)
               + dist3(p1.z, p1.w, p2.x, M)
               + dist3(p2.y, p2.z, p2.w, M);
    }
    #pragma unroll
    for (int off = 32; off > 0; off >>= 1)
        local += __shfl_down(local, off, 64);
    if (lane == 0) atomicAdd(out, local * SCALE);
}

extern "C" void kernel_launch(void* const* d_in, const int* in_sizes, int n_in,
                              void* d_out, int out_size, void* d_ws, size_t ws_size,
                              hipStream_t stream) {
    const float* pred  = (const float*)d_in[0];
    const float* mode  = (const float*)d_in[1];
    const float* gt    = (const float*)d_in[2];
    const float* point = (const float*)d_in[3];
    float* out = (float*)d_out;

    if (ws_size >= (size_t)B_ * sizeof(float)) {
        float* partial = (float*)d_ws;
        fused_main<<<NBLOCKS, NTHREADS, 0, stream>>>(pred, mode, gt, point, partial);
        reduce_kernel<<<1, 1024, 0, stream>>>(partial, out);
    } else {
        (void)hipMemsetAsync(out, 0, sizeof(float), stream);
        fused_atomic<<<NBLOCKS, NTHREADS, 0, stream>>>(pred, mode, gt, point, out);
    }
}

// Round 2
// 153.431 us; speedup vs baseline: 1.0206x; 1.0206x over previous
//
#include <hip/hip_runtime.h>
#include <math.h>

constexpr int B_ = 8192;
constexpr int N_ = 1024;
constexpr int NTHREADS = 256;
constexpr int WPB = NTHREADS / 64;        // 4 waves/block, one batch per wave
constexpr int NBLOCKS = B_ / WPB;         // 2048 blocks
constexpr float SCALE = 1.0f / ((float)B_ * (float)N_);
constexpr int ROWF = 3 * N_;              // floats per batch row (3072 = 12 KB)

// Native vector type (HIP_vector_type is rejected by some builtins).
typedef float vfloat4 __attribute__((ext_vector_type(4)));

// Address-space-qualified element types for global_load_lds.
typedef float GF __attribute__((address_space(1)));   // global
typedef float LF __attribute__((address_space(3)));   // LDS

// R = Rx(a) @ Ry(b) @ Rz(c), row-major 3x3 (matches reference euler_to_matrix_xyz)
__device__ __forceinline__ void euler_to_mat(float a, float b, float c, float R[9]) {
    float ca = cosf(a), sa = sinf(a);
    float cb = cosf(b), sb = sinf(b);
    float cc = cosf(c), sc = sinf(c);
    R[0] = cb * cc;                R[1] = -cb * sc;               R[2] = sb;
    R[3] = ca * sc + sa * sb * cc; R[4] = ca * cc - sa * sb * sc; R[5] = -sa * cb;
    R[6] = sa * sc - ca * sb * cc; R[7] = sa * cc + ca * sb * sc; R[8] = ca * cb;
}

// M = P - G from pre-loaded scalars (register-only; schedulable under load latency)
__device__ __forceinline__ void compute_M_vals(float m1, float m2, float m3, float m4,
                                               float md, float ga, float gb, float gc,
                                               float M[9]) {
    float sgn = (md > 0.5f) ? 1.0f : -1.0f;
    float e2 = sgn * asinf(sqrtf(m3 * m3 / (m1 * m1 + m2 * m2 + m3 * m3)));
    float e3 = atan2f(m4, m3 / (sinf(e2) + 1e-9f));
    float tmp = cosf(e2) * cosf(e3);
    float e1 = atan2f(m2 / tmp, m1 / tmp);
    e3 = (e3 > 0.0f) ? e3 : (e3 + 6.2831854820251465f); // float32(2*pi)
    float P[9], G[9];
    euler_to_mat(e1, e2, e3, P);
    euler_to_mat(ga, gb, gc, G);
    #pragma unroll
    for (int i = 0; i < 9; ++i) M[i] = P[i] - G[i];
}

__device__ __forceinline__ float dist3(float px, float py, float pz, const float* M) {
    float dx = px * M[0] + py * M[3] + pz * M[6];
    float dy = px * M[1] + py * M[4] + pz * M[7];
    float dz = px * M[2] + py * M[5] + pz * M[8];
    return sqrtf(dx * dx + dy * dy + dz * dz);
}

// ---------- Main: one batch per wave; global->LDS staging; NO barrier ----------
// v3: each wave reads only its own LDS region, so the v2 __syncthreads() (full
// vmcnt(0) drain + 4-wave coupling) is structurally unnecessary. Replaced with
// counted per-wave waits: issue all 12 staging loads, consume in 4 groups of 3
// with s_waitcnt vmcnt(9/6/3/0) -- group j's dist3 math overlaps groups j+1..3
// still in flight (T4: never drain to 0 before compute). Scalar pred/mode/gt
// loads are issued BEFORE the staging loads (compiler memory barrier between),
// so they are strictly OLDER in the in-order vmcnt retire stream and the
// counted waits remain conservative-correct even if they are vector loads.
// Per-lane arithmetic order identical to v2 -> bitwise-equal output.
__global__ __launch_bounds__(NTHREADS)
void fused_main(const float* __restrict__ pred, const float* __restrict__ mode,
                const float* __restrict__ gt, const float* __restrict__ point,
                float* __restrict__ partial)          // (B_,) one entry per wave/batch
{
    __shared__ __align__(16) float smem[WPB * ROWF];  // 48 KB -> 3 blocks/CU
    const int wave = threadIdx.x >> 6;
    const int lane = threadIdx.x & 63;
    const int b    = blockIdx.x * WPB + wave;

    // 1) Wave-uniform scalar inputs first (older than staging in the vm stream).
    const float m1 = pred[b * 4 + 0], m2 = pred[b * 4 + 1];
    const float m3 = pred[b * 4 + 2], m4 = pred[b * 4 + 3];
    const float md = mode[b];
    const float ga = gt[b * 3 + 0], gb = gt[b * 3 + 1], gc = gt[b * 3 + 2];

    asm volatile("" ::: "memory");   // order: staging loads issue after the above

    // 2) Stage this batch's 12 KB row: 12 x 1 KB lane-contiguous dwordx4,
    //    LDS dest linear (wave-uniform base + lane*16).
    {
        const float* src = point + (size_t)b * ROWF;
        float* dst = smem + wave * ROWF;
        #pragma unroll
        for (int i = 0; i < 12; ++i) {
            __builtin_amdgcn_global_load_lds(
                (const GF*)(src + i * 256 + lane * 4),
                (LF*)(dst + i * 256),
                16, 0, 0);
        }
    }

    // 3) M math (register-only), scheduled under the staging-load latency.
    float M[9];
    compute_M_vals(m1, m2, m3, m4, md, ga, gb, gc, M);

    // 4) Consume group j (3 loads = 768 floats = 4 points/lane) as soon as its
    //    loads retire; groups j+1.. remain in flight underneath the math.
    const float* lrow = smem + wave * ROWF;
    float local = 0.0f;

#define GROUP(J, CNT)                                                          \
    do {                                                                       \
        asm volatile("s_waitcnt vmcnt(" #CNT ")" ::: "memory");                \
        const vfloat4 p0 = *(const vfloat4*)(lrow + (J) * 768 + lane * 12 + 0);\
        const vfloat4 p1 = *(const vfloat4*)(lrow + (J) * 768 + lane * 12 + 4);\
        const vfloat4 p2 = *(const vfloat4*)(lrow + (J) * 768 + lane * 12 + 8);\
        local += dist3(p0.x, p0.y, p0.z, M)                                    \
               + dist3(p0.w, p1.x, p1.y, M)                                    \
               + dist3(p1.z, p1.w, p2.x, M)                                    \
               + dist3(p2.y, p2.z, p2.w, M);                                   \
    } while (0)

    GROUP(0, 9);
    GROUP(1, 6);
    GROUP(2, 3);
    GROUP(3, 0);
#undef GROUP

    // 5) Wave-local shuffle reduce; lane 0 stores this batch's sum.
    #pragma unroll
    for (int off = 32; off > 0; off >>= 1)
        local += __shfl_down(local, off, 64);
    if (lane == 0) partial[b] = local;
}

// ---------- Final: reduce 8192 partials -> scalar ----------
__global__ __launch_bounds__(1024)
void reduce_kernel(const float* __restrict__ partial, float* __restrict__ out) {
    __shared__ float swave[1024 / 64];
    const int t = threadIdx.x;
    float local = 0.0f;
    #pragma unroll
    for (int i = 0; i < B_ / 1024; ++i) local += partial[t + 1024 * i];
    #pragma unroll
    for (int off = 32; off > 0; off >>= 1)
        local += __shfl_down(local, off, 64);
    if ((t & 63) == 0) swave[t >> 6] = local;
    __syncthreads();
    if (t == 0) {
        float s = 0.0f;
        #pragma unroll
        for (int i = 0; i < 1024 / 64; ++i) s += swave[i];
        out[0] = s * SCALE;
    }
}

// ---------- Fallback (ws too small): v1 main, atomic into out ----------
__global__ __launch_bounds__(NTHREADS)
void fused_atomic(const float* __restrict__ pred, const float* __restrict__ mode,
                  const float* __restrict__ gt, const float* __restrict__ point,
                  float* __restrict__ out) {
    const int wave = threadIdx.x >> 6;
    const int lane = threadIdx.x & 63;
    const int b    = blockIdx.x * WPB + wave;
    const vfloat4* gp4 = (const vfloat4*)(point + (size_t)b * ROWF);
    vfloat4 P[4][3];
    #pragma unroll
    for (int j = 0; j < 4; ++j)
        #pragma unroll
        for (int k = 0; k < 3; ++k)
            P[j][k] = __builtin_nontemporal_load(&gp4[192 * j + 3 * lane + k]);
    const float m1 = pred[b * 4 + 0], m2 = pred[b * 4 + 1];
    const float m3 = pred[b * 4 + 2], m4 = pred[b * 4 + 3];
    float M[9];
    compute_M_vals(m1, m2, m3, m4, mode[b],
                   gt[b * 3 + 0], gt[b * 3 + 1], gt[b * 3 + 2], M);
    float local = 0.0f;
    #pragma unroll
    for (int j = 0; j < 4; ++j) {
        const vfloat4 p0 = P[j][0], p1 = P[j][1], p2 = P[j][2];
        local += dist3(p0.x, p0.y, p0.z, M)
               + dist3(p0.w, p1.x, p1.y, M)
               + dist3(p1.z, p1.w, p2.x, M)
               + dist3(p2.y, p2.z, p2.w, M);
    }
    #pragma unroll
    for (int off = 32; off > 0; off >>= 1)
        local += __shfl_down(local, off, 64);
    if (lane == 0) atomicAdd(out, local * SCALE);
}

extern "C" void kernel_launch(void* const* d_in, const int* in_sizes, int n_in,
                              void* d_out, int out_size, void* d_ws, size_t ws_size,
                              hipStream_t stream) {
    const float* pred  = (const float*)d_in[0];
    const float* mode  = (const float*)d_in[1];
    const float* gt    = (const float*)d_in[2];
    const float* point = (const float*)d_in[3];
    float* out = (float*)d_out;

    if (ws_size >= (size_t)B_ * sizeof(float)) {
        float* partial = (float*)d_ws;
        fused_main<<<NBLOCKS, NTHREADS, 0, stream>>>(pred, mode, gt, point, partial);
        reduce_kernel<<<1, 1024, 0, stream>>>(partial, out);
    } else {
        (void)hipMemsetAsync(out, 0, sizeof(float), stream);
        fused_atomic<<<NBLOCKS, NTHREADS, 0, stream>>>(pred, mode, gt, point, out);
    }
}